// Round 14
// baseline (125.316 us; speedup 1.0000x reference)
//
#include <hip/hip_runtime.h>
#include <hip/hip_bf16.h>
#include <math.h>

// GAT: B=4, N=2048, in=128, out=32, heads=4
// outputs: H_new [4,2048,128] f32 (1048576) then alpha [4,4,2048,2048] f32 (67108864)

typedef float f32x4 __attribute__((ext_vector_type(4)));
typedef short bf16x8 __attribute__((ext_vector_type(8)));
typedef unsigned int u32;

#define LRELU 0.2f
#define LOG2E 1.44269504088896f
#define EXP2(x) __builtin_amdgcn_exp2f(x)

__device__ inline ushort f2b(float x) {
    unsigned int u = __float_as_uint(x);
    u += 0x7fffu + ((u >> 16) & 1u);   // RNE
    return (ushort)(u >> 16);
}

// ---------------- k01: grid-union of adjM-pack (4096 blocks) and Ht MFMA (512 blocks) -----
__global__ __launch_bounds__(256) void k01(const float* __restrict__ adj,
                                           float* __restrict__ adjM,
                                           const float* __restrict__ H,
                                           const float* __restrict__ W,
                                           const float* __restrict__ a,
                                           __hip_bfloat16* __restrict__ HtT,
                                           float* __restrict__ src,
                                           float* __restrict__ dst) {
    __shared__ __align__(16) ushort Wbf[32 * 128];   // k1 path: W bf16 swizzled; reused as T

    int bid = blockIdx.x;
    int t = threadIdx.x;

    if (bid >= 512) {
        // ---- k0: adjM[row][col] = (adj!=0 || col==row) ? 1.0f : 0.0f ----
        int idx = (bid - 512) * 256 + t;
        int e0 = idx * 4;
        int row = e0 >> 11;
        int c0 = e0 & 2047;
        float4 v = *(const float4*)(adj + (size_t)e0);
        f32x4 o;
        o[0] = (v.x != 0.f || c0     == row) ? 1.f : 0.f;
        o[1] = (v.y != 0.f || c0 + 1 == row) ? 1.f : 0.f;
        o[2] = (v.z != 0.f || c0 + 2 == row) ? 1.f : 0.f;
        o[3] = (v.w != 0.f || c0 + 3 == row) ? 1.f : 0.f;
        *(f32x4*)(adjM + (size_t)e0) = o;
        return;
    }

    // ---- k1: Ht^T = W^T @ H^T (MFMA), + src/dst dots ----
    int ntile = bid & 31;
    int bh = bid >> 5;
    int b = bh >> 2, h = bh & 3;
    int lane = t & 63, w = t >> 6;
    int l15 = lane & 15, l4 = lane >> 4;

    #pragma unroll
    for (int u = 0; u < 16; ++u) {
        int idx = u * 256 + t;
        int i = idx >> 5, f = idx & 31;
        Wbf[(f * 128 + i) ^ ((f & 7) << 3)] = f2b(W[h * 4096 + idx]);
    }
    __syncthreads();

    int n = ntile * 64 + w * 16 + l15;
    const float* hrow = H + ((size_t)(b * 2048) + n) * 128;

    f32x4 acc0 = {0.f, 0.f, 0.f, 0.f};   // f rows 0-15
    f32x4 acc1 = {0.f, 0.f, 0.f, 0.f};   // f rows 16-31
    #pragma unroll
    for (int kc = 0; kc < 4; ++kc) {
        int k0 = kc * 32 + l4 * 8;
        float4 h0 = *(const float4*)(hrow + k0);
        float4 h1 = *(const float4*)(hrow + k0 + 4);
        union { u32 u[4]; bf16x8 v; } bu;
        asm("v_cvt_pk_bf16_f32 %0, %1, %2" : "=v"(bu.u[0]) : "v"(h0.x), "v"(h0.y));
        asm("v_cvt_pk_bf16_f32 %0, %1, %2" : "=v"(bu.u[1]) : "v"(h0.z), "v"(h0.w));
        asm("v_cvt_pk_bf16_f32 %0, %1, %2" : "=v"(bu.u[2]) : "v"(h1.x), "v"(h1.y));
        asm("v_cvt_pk_bf16_f32 %0, %1, %2" : "=v"(bu.u[3]) : "v"(h1.z), "v"(h1.w));
        bf16x8 bfrag = bu.v;
        bf16x8 af0 = *(const bf16x8*)&Wbf[(l15 * 128 + kc * 32 + l4 * 8) ^ ((l15 & 7) << 3)];
        bf16x8 af1 = *(const bf16x8*)&Wbf[((16 + l15) * 128 + kc * 32 + l4 * 8) ^ (((16 + l15) & 7) << 3)];
        acc0 = __builtin_amdgcn_mfma_f32_16x16x32_bf16(af0, bfrag, acc0, 0, 0, 0);
        acc1 = __builtin_amdgcn_mfma_f32_16x16x32_bf16(af1, bfrag, acc1, 0, 0, 0);
    }

    // src/dst dots from accumulators
    float sv = 0.f, dvv = 0.f;
    #pragma unroll
    for (int r = 0; r < 4; ++r) {
        int f0 = l4 * 4 + r;
        sv  += acc0[r] * a[h * 64 + f0]      + acc1[r] * a[h * 64 + 16 + f0];
        dvv += acc0[r] * a[h * 64 + 32 + f0] + acc1[r] * a[h * 64 + 48 + f0];
    }
    sv  += __shfl_xor(sv, 16);  sv  += __shfl_xor(sv, 32);
    dvv += __shfl_xor(dvv, 16); dvv += __shfl_xor(dvv, 32);
    if (l4 == 0) { src[bh * 2048 + n] = sv; dst[bh * 2048 + n] = dvv; }

    // HtT via LDS transpose (reuse Wbf as T[32 f][64 n]) for coalesced 16B stores
    __syncthreads();
    ushort* T = Wbf;
    int nl = w * 16 + l15;
    #pragma unroll
    for (int r = 0; r < 4; ++r) {
        int f0 = l4 * 4 + r;
        T[f0 * 64 + nl]        = f2b(acc0[r]);
        T[(16 + f0) * 64 + nl] = f2b(acc1[r]);
    }
    __syncthreads();
    {
        int f = t >> 3, n8 = (t & 7) * 8;
        uint4 v = *(const uint4*)&T[f * 64 + n8];
        *(uint4*)((ushort*)HtT + (size_t)(bh * 32 + f) * 2048 + ntile * 64 + n8) = v;
    }
}

// ---------------- k2: fragment-native softmax, K-split 4, short-lived churn ----------------
// grid (128 mtiles of 16 rows, 16 bh), block 256 = 4 waves. Wave ks owns cols [ks*512,+512).
// Lane layout == MFMA A-fragment: row = lane&15, k = (lane>>4)*8 + i. Softmax is computed
// straight into registers; alpha stores and the MFMA A operand come from the same o[] —
// no As LDS, no per-chunk barriers, no cvt roundtrip. 3 lgkm-only barriers per block.
// Waves retire with stores in flight; 8192-wave churn keeps the HBM write queue full.
__global__ __launch_bounds__(256, 4) void k2_fused(const float* __restrict__ adjM,
                                                   const float* __restrict__ src,
                                                   const float* __restrict__ dst,
                                                   const __hip_bfloat16* __restrict__ HtT,
                                                   float* __restrict__ alpha,
                                                   float* __restrict__ outH) {
    __shared__ float dstS[2048];            // 8 KB, pre-scaled by LOG2E
    __shared__ float Scomb[4][16];
    __shared__ float AccComb[3 * 528];      // 3 ksplit partials, [16][33] padded

    int t = threadIdx.x;
    int lane = t & 63, ks = t >> 6;
    int mtile = blockIdx.x;   // 128
    int bh    = blockIdx.y;   // 16
    int b = bh >> 2, h = bh & 3;
    int row0 = mtile * 16;
    int l15 = lane & 15, l4 = lane >> 4;

    // stage dstS (all 4 waves cooperate)
    const float4* dst4g = (const float4*)(dst + bh * 2048);
    #pragma unroll
    for (int u = 0; u < 2; ++u) {
        float4 v = dst4g[u * 256 + t];
        v.x *= LOG2E; v.y *= LOG2E; v.z *= LOG2E; v.w *= LOG2E;
        *(float4*)&dstS[(u * 256 + t) * 4] = v;
    }
    asm volatile("s_waitcnt lgkmcnt(0)" ::: "memory");
    __builtin_amdgcn_s_barrier();

    int gr = row0 + l15;                     // this lane's row
    float sn = src[bh * 2048 + gr] * LOG2E;
    const float* amRow = adjM + (size_t)gr * 2048;

    // ---- pass A: partial S over this wave's 512 cols, lane-parallel ----
    float S = 0.f;
    for (int c = 0; c < 16; ++c) {
        int k0 = ks * 512 + c * 32 + l4 * 8;
        float4 a0 = *(const float4*)(amRow + k0);
        float4 a1 = *(const float4*)(amRow + k0 + 4);
        float4 d0 = *(const float4*)&dstS[k0];
        float4 d1 = *(const float4*)&dstS[k0 + 4];
        float am[8] = {a0.x, a0.y, a0.z, a0.w, a1.x, a1.y, a1.z, a1.w};
        float dj[8] = {d0.x, d0.y, d0.z, d0.w, d1.x, d1.y, d1.z, d1.w};
        #pragma unroll
        for (int i = 0; i < 8; ++i) {
            float ee = sn + dj[i];
            float vm = fmaxf(ee, LRELU * ee);
            S = fmaf(EXP2(vm), am[i], S);
        }
    }
    S += __shfl_xor(S, 16);
    S += __shfl_xor(S, 32);
    if (l4 == 0) Scomb[ks][l15] = S;
    asm volatile("s_waitcnt lgkmcnt(0)" ::: "memory");
    __builtin_amdgcn_s_barrier();

    float Sf = (Scomb[0][l15] + Scomb[1][l15]) + (Scomb[2][l15] + Scomb[3][l15]);
    float L = -__log2f(Sf);
    float snL = sn + L;          // ee+L in one add
    float L08 = 0.8f * L;        // 0.2*ee + L = fma(eeL, 0.2, 0.8L)

    // ---- pass B: 16 chunks of 32 cols, stores from fragment-layout registers ----
    f32x4 acc0 = {0.f, 0.f, 0.f, 0.f};      // out cols 0-15
    f32x4 acc1 = {0.f, 0.f, 0.f, 0.f};      // out cols 16-31
    const ushort* Bp0 = (const ushort*)HtT + (size_t)(bh * 32 + l15) * 2048;
    const ushort* Bp1 = (const ushort*)HtT + (size_t)(bh * 32 + 16 + l15) * 2048;
    float* aRow = alpha + (size_t)(bh * 2048 + gr) * 2048;

    float amE[8], amO[8];
    bf16x8 bE0, bE1, bO0, bO1;

    auto loadAM = [&](int c, float* am) {
        int k0 = ks * 512 + c * 32 + l4 * 8;
        float4 a0 = *(const float4*)(amRow + k0);
        float4 a1 = *(const float4*)(amRow + k0 + 4);
        am[0] = a0.x; am[1] = a0.y; am[2] = a0.z; am[3] = a0.w;
        am[4] = a1.x; am[5] = a1.y; am[6] = a1.z; am[7] = a1.w;
    };
    auto loadB2 = [&](int c, bf16x8& b0, bf16x8& b1) {
        int k0 = ks * 512 + c * 32 + l4 * 8;
        b0 = *(const bf16x8*)(Bp0 + k0);
        b1 = *(const bf16x8*)(Bp1 + k0);
    };
    auto chunkB = [&](int c, const float* am, bf16x8 b0, bf16x8 b1) {
        int k0 = ks * 512 + c * 32 + l4 * 8;
        float4 d0 = *(const float4*)&dstS[k0];
        float4 d1 = *(const float4*)&dstS[k0 + 4];
        float dj[8] = {d0.x, d0.y, d0.z, d0.w, d1.x, d1.y, d1.z, d1.w};
        float o[8];
        #pragma unroll
        for (int i = 0; i < 8; ++i) {
            float eeL = snL + dj[i];
            float tt = fmaf(eeL, LRELU, L08);
            float vm = fmaxf(eeL, tt);
            o[i] = EXP2(vm) * am[i];
        }
        f32x4 ov0 = {o[0], o[1], o[2], o[3]};
        f32x4 ov1 = {o[4], o[5], o[6], o[7]};
        *(f32x4*)(aRow + k0) = ov0;
        *(f32x4*)(aRow + k0 + 4) = ov1;
        union { u32 u[4]; bf16x8 v; } au;
        asm("v_cvt_pk_bf16_f32 %0, %1, %2" : "=v"(au.u[0]) : "v"(o[0]), "v"(o[1]));
        asm("v_cvt_pk_bf16_f32 %0, %1, %2" : "=v"(au.u[1]) : "v"(o[2]), "v"(o[3]));
        asm("v_cvt_pk_bf16_f32 %0, %1, %2" : "=v"(au.u[2]) : "v"(o[4]), "v"(o[5]));
        asm("v_cvt_pk_bf16_f32 %0, %1, %2" : "=v"(au.u[3]) : "v"(o[6]), "v"(o[7]));
        acc0 = __builtin_amdgcn_mfma_f32_16x16x32_bf16(au.v, b0, acc0, 0, 0, 0);
        acc1 = __builtin_amdgcn_mfma_f32_16x16x32_bf16(au.v, b1, acc1, 0, 0, 0);
    };

    loadAM(0, amE); loadB2(0, bE0, bE1);
    #pragma unroll
    for (int cp = 0; cp < 8; ++cp) {
        int ce = 2 * cp, co = ce + 1;
        loadAM(co, amO); loadB2(co, bO0, bO1);    // loads BEFORE chunk ce's stores
        __builtin_amdgcn_sched_barrier(0);
        chunkB(ce, amE, bE0, bE1);
        if (co < 15) { loadAM(co + 1, amE); loadB2(co + 1, bE0, bE1); }
        __builtin_amdgcn_sched_barrier(0);
        chunkB(co, amO, bO0, bO1);
    }

    // ---- epilogue: combine K-split partials, ELU, outH ----
    if (ks != 0) {
        #pragma unroll
        for (int q = 0; q < 4; ++q) {
            int row = l4 * 4 + q;
            AccComb[(ks - 1) * 528 + row * 33 + l15]      = acc0[q];
            AccComb[(ks - 1) * 528 + row * 33 + 16 + l15] = acc1[q];
        }
    }
    asm volatile("s_waitcnt lgkmcnt(0)" ::: "memory");
    __builtin_amdgcn_s_barrier();
    if (ks == 0) {
        #pragma unroll
        for (int q = 0; q < 4; ++q) {
            int row = l4 * 4 + q;
            float v0 = acc0[q], v1 = acc1[q];
            #pragma unroll
            for (int j = 0; j < 3; ++j) {
                v0 += AccComb[j * 528 + row * 33 + l15];
                v1 += AccComb[j * 528 + row * 33 + 16 + l15];
            }
            v0 = (v0 > 0.f) ? v0 : expm1f(v0);
            v1 = (v1 > 0.f) ? v1 : expm1f(v1);
            size_t base = (size_t)(b * 2048 + row0 + row) * 128 + h * 32;
            outH[base + l15]      = v0;
            outH[base + 16 + l15] = v1;
        }
    }
}

extern "C" void kernel_launch(void* const* d_in, const int* in_sizes, int n_in,
                              void* d_out, int out_size, void* d_ws, size_t ws_size,
                              hipStream_t stream) {
    const float* H   = (const float*)d_in[0];
    const float* adj = (const float*)d_in[1];
    const float* W   = (const float*)d_in[2];
    const float* a   = (const float*)d_in[3];

    float* outH  = (float*)d_out;
    float* alpha = outH + (size_t)4 * 2048 * 128;   // 1048576

    char* ws = (char*)d_ws;
    __hip_bfloat16* HtT = (__hip_bfloat16*)ws;                    // 2 MB
    float* src  = (float*)(ws + 2 * 1024 * 1024);                 // 128 KB
    float* dst  = src + 32768;                                    // 128 KB
    float* adjM = (float*)(ws + 2 * 1024 * 1024 + 256 * 1024);    // 16 MB (f32 0/1 mask)

    k01<<<4608, 256, 0, stream>>>(adj, adjM, H, W, a, HtT, src, dst);
    k2_fused<<<dim3(128, 16), 256, 0, stream>>>(adjM, src, dst, HtT, alpha, outH);
}

// Round 15
// 80.678 us; speedup vs baseline: 1.5533x; 1.5533x over previous
//
#include <hip/hip_runtime.h>
#include <hip/hip_bf16.h>
#include <math.h>

// GAT: B=4, N=2048, in=128, out=32, heads=4
// outputs: H_new [4,2048,128] f32 (1048576) then alpha [4,4,2048,2048] f32 (67108864)

typedef float f32x4 __attribute__((ext_vector_type(4)));
typedef short bf16x8 __attribute__((ext_vector_type(8)));
typedef unsigned int u32;

#define LRELU 0.2f
#define LOG2E 1.44269504088896f
#define EXP2(x) __builtin_amdgcn_exp2f(x)

__device__ inline ushort f2b(float x) {
    unsigned int u = __float_as_uint(x);
    u += 0x7fffu + ((u >> 16) & 1u);   // RNE
    return (ushort)(u >> 16);
}

// ---------------- k01: grid-union of adjI-pack (4096 blocks) and Ht MFMA (512 blocks) -----
__global__ __launch_bounds__(256) void k01(const float* __restrict__ adj,
                                           unsigned char* __restrict__ adjI,
                                           const float* __restrict__ H,
                                           const float* __restrict__ W,
                                           const float* __restrict__ a,
                                           __hip_bfloat16* __restrict__ HtT,
                                           float* __restrict__ src,
                                           float* __restrict__ dst) {
    __shared__ __align__(16) ushort Wbf[32 * 128];   // k1 path: W bf16 swizzled; reused as T

    int bid = blockIdx.x;
    int t = threadIdx.x;

    if (bid >= 512) {
        // ---- k0: adjI[row][col] = (adj!=0 || col==row) ----
        int idx = (bid - 512) * 256 + t;
        int e0 = idx * 4;
        int row = e0 >> 11;
        int c0 = e0 & 2047;
        float4 v = *(const float4*)(adj + (size_t)e0);
        uchar4 o;
        o.x = (v.x != 0.f || c0     == row) ? 1 : 0;
        o.y = (v.y != 0.f || c0 + 1 == row) ? 1 : 0;
        o.z = (v.z != 0.f || c0 + 2 == row) ? 1 : 0;
        o.w = (v.w != 0.f || c0 + 3 == row) ? 1 : 0;
        *(uchar4*)(adjI + (size_t)e0) = o;
        return;
    }

    // ---- k1: Ht^T = W^T @ H^T (MFMA), + src/dst dots ----
    int ntile = bid & 31;
    int bh = bid >> 5;
    int b = bh >> 2, h = bh & 3;
    int lane = t & 63, w = t >> 6;
    int l15 = lane & 15, l4 = lane >> 4;

    #pragma unroll
    for (int u = 0; u < 16; ++u) {
        int idx = u * 256 + t;
        int i = idx >> 5, f = idx & 31;
        Wbf[(f * 128 + i) ^ ((f & 7) << 3)] = f2b(W[h * 4096 + idx]);
    }
    __syncthreads();

    int n = ntile * 64 + w * 16 + l15;
    const float* hrow = H + ((size_t)(b * 2048) + n) * 128;

    f32x4 acc0 = {0.f, 0.f, 0.f, 0.f};   // f rows 0-15
    f32x4 acc1 = {0.f, 0.f, 0.f, 0.f};   // f rows 16-31
    #pragma unroll
    for (int kc = 0; kc < 4; ++kc) {
        int k0 = kc * 32 + l4 * 8;
        float4 h0 = *(const float4*)(hrow + k0);
        float4 h1 = *(const float4*)(hrow + k0 + 4);
        union { u32 u[4]; bf16x8 v; } bu;
        asm("v_cvt_pk_bf16_f32 %0, %1, %2" : "=v"(bu.u[0]) : "v"(h0.x), "v"(h0.y));
        asm("v_cvt_pk_bf16_f32 %0, %1, %2" : "=v"(bu.u[1]) : "v"(h0.z), "v"(h0.w));
        asm("v_cvt_pk_bf16_f32 %0, %1, %2" : "=v"(bu.u[2]) : "v"(h1.x), "v"(h1.y));
        asm("v_cvt_pk_bf16_f32 %0, %1, %2" : "=v"(bu.u[3]) : "v"(h1.z), "v"(h1.w));
        bf16x8 bfrag = bu.v;
        bf16x8 af0 = *(const bf16x8*)&Wbf[(l15 * 128 + kc * 32 + l4 * 8) ^ ((l15 & 7) << 3)];
        bf16x8 af1 = *(const bf16x8*)&Wbf[((16 + l15) * 128 + kc * 32 + l4 * 8) ^ (((16 + l15) & 7) << 3)];
        acc0 = __builtin_amdgcn_mfma_f32_16x16x32_bf16(af0, bfrag, acc0, 0, 0, 0);
        acc1 = __builtin_amdgcn_mfma_f32_16x16x32_bf16(af1, bfrag, acc1, 0, 0, 0);
    }

    // src/dst dots from accumulators
    float sv = 0.f, dvv = 0.f;
    #pragma unroll
    for (int r = 0; r < 4; ++r) {
        int f0 = l4 * 4 + r;
        sv  += acc0[r] * a[h * 64 + f0]      + acc1[r] * a[h * 64 + 16 + f0];
        dvv += acc0[r] * a[h * 64 + 32 + f0] + acc1[r] * a[h * 64 + 48 + f0];
    }
    sv  += __shfl_xor(sv, 16);  sv  += __shfl_xor(sv, 32);
    dvv += __shfl_xor(dvv, 16); dvv += __shfl_xor(dvv, 32);
    if (l4 == 0) { src[bh * 2048 + n] = sv; dst[bh * 2048 + n] = dvv; }

    // HtT via LDS transpose (reuse Wbf as T[32 f][64 n]) for coalesced 16B stores
    __syncthreads();
    ushort* T = Wbf;
    int nl = w * 16 + l15;
    #pragma unroll
    for (int r = 0; r < 4; ++r) {
        int f0 = l4 * 4 + r;
        T[f0 * 64 + nl]        = f2b(acc0[r]);
        T[(16 + f0) * 64 + nl] = f2b(acc1[r]);
    }
    __syncthreads();
    {
        int f = t >> 3, n8 = (t & 7) * 8;
        uint4 v = *(const uint4*)&T[f * 64 + n8];
        *(uint4*)((ushort*)HtT + (size_t)(bh * 32 + f) * 2048 + ntile * 64 + n8) = v;
    }
}

// ---------------- k2: 2-tile pipeline — T1's pass A hides under T0's store drain -----------
// grid (32 tile-pairs, 16 bh), block 256 (4 waves). Each block: passA(T0); 16-chunk store
// loop for T0 with T1's pass-A slice interleaved in the store-backpressure window; then
// T1's 16-chunk store loop. Loads always issued before stores; one lgkm-only barrier per
// chunk; alpha stores keep R11's coalesced two-512B-segments-per-wave shape.
__global__ __launch_bounds__(256, 4) void k2_fused(const unsigned char* __restrict__ adjI,
                                                   const float* __restrict__ src,
                                                   const float* __restrict__ dst,
                                                   const __hip_bfloat16* __restrict__ HtT,
                                                   float* __restrict__ alpha,
                                                   float* __restrict__ outH) {
    __shared__ float dstS[2048];                      // 8 KB (pre-scaled by LOG2E)
    __shared__ float rowL[32], rowSrcS[32];           // current-tile constants (reused)
    __shared__ float rowSrc1[32], rowS1[32];          // T1 src + S partials
    __shared__ __align__(16) ushort As[2][32 * 128];  // 16 KB dbuf, XOR-swizzled

    int t = threadIdx.x;
    int pair = blockIdx.x;    // 32
    int bh   = blockIdx.y;    // 16
    int lane = t & 63, w = t >> 6;
    int b = bh >> 2, h = bh & 3;
    int row0 = pair * 64;     // T0 rows [row0, +32), T1 rows [row0+32, +32)
    int row1 = row0 + 32;

    const float4* dst4g = (const float4*)(dst + bh * 2048);
    #pragma unroll
    for (int u = 0; u < 2; ++u) {
        float4 v = dst4g[u * 256 + t];
        v.x *= LOG2E; v.y *= LOG2E; v.z *= LOG2E; v.w *= LOG2E;
        *(float4*)&dstS[(u * 256 + t) * 4] = v;
    }
    if (t < 32)      rowSrcS[t]      = src[bh * 2048 + row0 + t] * LOG2E;
    else if (t < 64) rowSrc1[t - 32] = src[bh * 2048 + row1 + (t - 32)] * LOG2E;
    __syncthreads();

    // ---- pass A for T0: per-row S = sum_j adjI * exp2(leaky(ee)); L = -log2(S) ----
    for (int rr = 0; rr < 8; ++rr) {
        int r = w * 8 + rr;
        int gr = row0 + r;
        float sn = rowSrcS[r];
        const uint4* a16 = (const uint4*)(adjI + (size_t)gr * 2048);
        float S = 0.f;
        #pragma unroll
        for (int u = 0; u < 2; ++u) {
            uint4 ab = a16[u * 64 + lane];
            int jb = (u * 64 + lane) * 16;
            u32 words[4] = {ab.x, ab.y, ab.z, ab.w};
            #pragma unroll
            for (int wq = 0; wq < 4; ++wq) {
                float4 dv = *(const float4*)&dstS[jb + wq * 4];
                float dj[4] = {dv.x, dv.y, dv.z, dv.w};
                #pragma unroll
                for (int q = 0; q < 4; ++q) {
                    float ajf = (float)((words[wq] >> (8 * q)) & 0xffu);
                    float ee = sn + dj[q];
                    float vm = fmaxf(ee, LRELU * ee);
                    S = fmaf(EXP2(vm), ajf, S);
                }
            }
        }
        #pragma unroll
        for (int off = 32; off; off >>= 1) S += __shfl_xor(S, off);
        if (lane == 0) rowL[r] = -__log2f(S);
    }
    __syncthreads();

    // ---- shared pass-B machinery ----
    int wr = w >> 1, wc = w & 1;
    int l15 = lane & 15, l4 = lane >> 4;
    int arow = wr * 16 + l15;
    const ushort* Bfp = (const ushort*)HtT + (size_t)(bh * 32 + wc * 16 + l15) * 2048 + l4 * 8;
    int sr = t >> 5;            // As rows sr, sr+8, sr+16, sr+24
    int sc4 = t & 31;

    float snR[4], LR[4];
    float* aRowBase;            // set per tile
    int rowBase;                // set per tile

    auto loadA = [&](int k, u32* ar) {
        #pragma unroll
        for (int u = 0; u < 4; ++u)
            ar[u] = *(const u32*)(adjI + (size_t)(rowBase + sr + u * 8) * 2048 + k * 128 + sc4 * 4);
    };
    auto stage = [&](int k, const u32* ar, ushort* Asb) {
        int jb = k * 128 + sc4 * 4;
        float4 dv = *(const float4*)&dstS[jb];
        float dj[4] = {dv.x, dv.y, dv.z, dv.w};
        #pragma unroll
        for (int u = 0; u < 4; ++u) {
            int r = sr + u * 8;
            float sn = snR[u], L = LR[u];
            u32 ab = ar[u];
            float o[4];
            #pragma unroll
            for (int q = 0; q < 4; ++q) {
                float ajf = (float)((ab >> (8 * q)) & 0xffu);
                float ee = sn + dj[q];
                float vm = fmaxf(ee + L, fmaf(ee, LRELU, L));
                o[q] = EXP2(vm) * ajf;
            }
            f32x4 ov = {o[0], o[1], o[2], o[3]};
            *(f32x4*)(aRowBase + (size_t)r * 2048 + jb) = ov;
            u32 lo, hi;
            asm("v_cvt_pk_bf16_f32 %0, %1, %2" : "=v"(lo) : "v"(o[0]), "v"(o[1]));
            asm("v_cvt_pk_bf16_f32 %0, %1, %2" : "=v"(hi) : "v"(o[2]), "v"(o[3]));
            uint2 pk = {lo, hi};
            *(uint2*)&Asb[(r * 128 + sc4 * 4) ^ ((r & 7) << 3)] = pk;
        }
    };

    f32x4 acc = {0.f, 0.f, 0.f, 0.f};
    auto mfmaPhase = [&](const bf16x8* br, const ushort* Asb) {
        #pragma unroll
        for (int kk = 0; kk < 4; ++kk) {
            bf16x8 af = *(const bf16x8*)&Asb[(arow * 128 + kk * 32 + l4 * 8) ^ ((arow & 7) << 3)];
            acc = __builtin_amdgcn_mfma_f32_16x16x32_bf16(af, br[kk], acc, 0, 0, 0);
        }
    };
    auto outEpi = [&](int rb) {
        #pragma unroll
        for (int q = 0; q < 4; ++q) {
            int node = rb + wr * 16 + l4 * 4 + q;
            float v = acc[q];
            v = (v > 0.f) ? v : expm1f(v);
            outH[(size_t)(b * 2048 + node) * 128 + h * 32 + wc * 16 + l15] = v;
        }
    };

    // ---- T1 pass-A slice state: lane handles rows w*8 + rp*2 + hi, cols (lane&31)*4 ----
    int hi = lane >> 5;
    int c32 = (lane & 31) * 4;
    float snT1[4], Sacc[4] = {0.f, 0.f, 0.f, 0.f};
    #pragma unroll
    for (int rp = 0; rp < 4; ++rp) snT1[rp] = rowSrc1[w * 8 + rp * 2 + hi];

    // ================= T0 chunk loop (with T1 pass-A slices interleaved) =================
    rowBase = row0;
    aRowBase = alpha + (size_t)(bh * 2048 + row0) * 2048;
    #pragma unroll
    for (int u = 0; u < 4; ++u) { snR[u] = rowSrcS[sr + u * 8]; LR[u] = rowL[sr + u * 8]; }

    u32 aE[4], aO[4];
    loadA(0, aE);
    for (int kc = 0; kc < 16; ++kc) {
        const u32* aC = (kc & 1) ? aO : aE;
        u32*       aN = (kc & 1) ? aE : aO;
        // --- all loads first (before this chunk's stores) ---
        bf16x8 bf[4];
        #pragma unroll
        for (int kk = 0; kk < 4; ++kk)
            bf[kk] = *(const bf16x8*)(Bfp + (size_t)kc * 128 + kk * 32);
        u32 ab1[4];
        #pragma unroll
        for (int rp = 0; rp < 4; ++rp)
            ab1[rp] = *(const u32*)(adjI + (size_t)(row1 + w * 8 + rp * 2 + hi) * 2048 + kc * 128 + c32);
        if (kc < 15) loadA(kc + 1, aN);
        __builtin_amdgcn_sched_barrier(0);
        // --- T0 stage: alpha stores + As fill ---
        stage(kc, aC, As[kc & 1]);
        // --- T1 pass-A slice (VALU in the store-backpressure window) ---
        {
            float4 dv = *(const float4*)&dstS[kc * 128 + c32];
            float dj[4] = {dv.x, dv.y, dv.z, dv.w};
            #pragma unroll
            for (int rp = 0; rp < 4; ++rp) {
                float sn = snT1[rp];
                u32 ab = ab1[rp];
                #pragma unroll
                for (int q = 0; q < 4; ++q) {
                    float ajf = (float)((ab >> (8 * q)) & 0xffu);
                    float ee = sn + dj[q];
                    float vm = fmaxf(ee, LRELU * ee);
                    Sacc[rp] = fmaf(EXP2(vm), ajf, Sacc[rp]);
                }
            }
        }
        asm volatile("s_waitcnt lgkmcnt(0)" ::: "memory");
        __builtin_amdgcn_s_barrier();
        mfmaPhase(bf, As[kc & 1]);
    }
    outEpi(row0);

    // ---- finalize T1 row sums ----
    #pragma unroll
    for (int rp = 0; rp < 4; ++rp) {
        float s = Sacc[rp];
        s += __shfl_xor(s, 1);  s += __shfl_xor(s, 2);  s += __shfl_xor(s, 4);
        s += __shfl_xor(s, 8);  s += __shfl_xor(s, 16);
        if ((lane & 31) == 0) rowS1[w * 8 + rp * 2 + hi] = s;
    }
    asm volatile("s_waitcnt lgkmcnt(0)" ::: "memory");
    __builtin_amdgcn_s_barrier();

    // ================= T1 chunk loop (plain) =================
    rowBase = row1;
    aRowBase = alpha + (size_t)(bh * 2048 + row1) * 2048;
    #pragma unroll
    for (int u = 0; u < 4; ++u) { snR[u] = rowSrc1[sr + u * 8]; LR[u] = -__log2f(rowS1[sr + u * 8]); }
    acc[0] = acc[1] = acc[2] = acc[3] = 0.f;

    loadA(0, aE);
    for (int kc = 0; kc < 16; ++kc) {
        const u32* aC = (kc & 1) ? aO : aE;
        u32*       aN = (kc & 1) ? aE : aO;
        bf16x8 bf[4];
        #pragma unroll
        for (int kk = 0; kk < 4; ++kk)
            bf[kk] = *(const bf16x8*)(Bfp + (size_t)kc * 128 + kk * 32);
        if (kc < 15) loadA(kc + 1, aN);
        __builtin_amdgcn_sched_barrier(0);
        stage(kc, aC, As[kc & 1]);
        asm volatile("s_waitcnt lgkmcnt(0)" ::: "memory");
        __builtin_amdgcn_s_barrier();
        mfmaPhase(bf, As[kc & 1]);
    }
    outEpi(row1);
}

extern "C" void kernel_launch(void* const* d_in, const int* in_sizes, int n_in,
                              void* d_out, int out_size, void* d_ws, size_t ws_size,
                              hipStream_t stream) {
    const float* H   = (const float*)d_in[0];
    const float* adj = (const float*)d_in[1];
    const float* W   = (const float*)d_in[2];
    const float* a   = (const float*)d_in[3];

    float* outH  = (float*)d_out;
    float* alpha = outH + (size_t)4 * 2048 * 128;   // 1048576

    char* ws = (char*)d_ws;
    __hip_bfloat16* HtT = (__hip_bfloat16*)ws;                    // 2 MB
    float* src = (float*)(ws + 2 * 1024 * 1024);                  // 128 KB
    float* dst = src + 32768;                                     // 128 KB
    unsigned char* adjI = (unsigned char*)(ws + 2 * 1024 * 1024 + 256 * 1024);  // 4 MB

    k01<<<4608, 256, 0, stream>>>(adj, adjI, H, W, a, HtT, src, dst);
    k2_fused<<<dim3(32, 16), 256, 0, stream>>>(adjI, src, dst, HtT, alpha, outH);
}

// Round 16
// 70.938 us; speedup vs baseline: 1.7665x; 1.1373x over previous
//
#include <hip/hip_runtime.h>
#include <hip/hip_bf16.h>
#include <math.h>

// GAT: B=4, N=2048, in=128, out=32, heads=4
// outputs: H_new [4,2048,128] f32 (1048576) then alpha [4,4,2048,2048] f32 (67108864)

typedef float f32x4 __attribute__((ext_vector_type(4)));
typedef short bf16x8 __attribute__((ext_vector_type(8)));
typedef unsigned int u32;

#define LRELU 0.2f
#define LOG2E 1.44269504088896f
#define EXP2(x) __builtin_amdgcn_exp2f(x)

__device__ inline ushort f2b(float x) {
    unsigned int u = __float_as_uint(x);
    u += 0x7fffu + ((u >> 16) & 1u);   // RNE
    return (ushort)(u >> 16);
}

// ---------------- k01: grid-union of adjI-pack (4096 blocks) and Ht MFMA (512 blocks) -----
__global__ __launch_bounds__(256) void k01(const float* __restrict__ adj,
                                           unsigned char* __restrict__ adjI,
                                           const float* __restrict__ H,
                                           const float* __restrict__ W,
                                           const float* __restrict__ a,
                                           __hip_bfloat16* __restrict__ HtT,
                                           float* __restrict__ src,
                                           float* __restrict__ dst) {
    __shared__ __align__(16) ushort Wbf[32 * 128];   // k1 path: W bf16 swizzled; reused as T

    int bid = blockIdx.x;
    int t = threadIdx.x;

    if (bid >= 512) {
        // ---- k0: adjI[row][col] = (adj!=0 || col==row) ----
        int idx = (bid - 512) * 256 + t;
        int e0 = idx * 4;
        int row = e0 >> 11;
        int c0 = e0 & 2047;
        float4 v = *(const float4*)(adj + (size_t)e0);
        uchar4 o;
        o.x = (v.x != 0.f || c0     == row) ? 1 : 0;
        o.y = (v.y != 0.f || c0 + 1 == row) ? 1 : 0;
        o.z = (v.z != 0.f || c0 + 2 == row) ? 1 : 0;
        o.w = (v.w != 0.f || c0 + 3 == row) ? 1 : 0;
        *(uchar4*)(adjI + (size_t)e0) = o;
        return;
    }

    // ---- k1: Ht^T = W^T @ H^T (MFMA), + src/dst dots ----
    int ntile = bid & 31;
    int bh = bid >> 5;
    int b = bh >> 2, h = bh & 3;
    int lane = t & 63, w = t >> 6;
    int l15 = lane & 15, l4 = lane >> 4;

    #pragma unroll
    for (int u = 0; u < 16; ++u) {
        int idx = u * 256 + t;
        int i = idx >> 5, f = idx & 31;
        Wbf[(f * 128 + i) ^ ((f & 7) << 3)] = f2b(W[h * 4096 + idx]);
    }
    __syncthreads();

    int n = ntile * 64 + w * 16 + l15;
    const float* hrow = H + ((size_t)(b * 2048) + n) * 128;

    f32x4 acc0 = {0.f, 0.f, 0.f, 0.f};   // f rows 0-15
    f32x4 acc1 = {0.f, 0.f, 0.f, 0.f};   // f rows 16-31
    #pragma unroll
    for (int kc = 0; kc < 4; ++kc) {
        int k0 = kc * 32 + l4 * 8;
        float4 h0 = *(const float4*)(hrow + k0);
        float4 h1 = *(const float4*)(hrow + k0 + 4);
        union { u32 u[4]; bf16x8 v; } bu;
        asm("v_cvt_pk_bf16_f32 %0, %1, %2" : "=v"(bu.u[0]) : "v"(h0.x), "v"(h0.y));
        asm("v_cvt_pk_bf16_f32 %0, %1, %2" : "=v"(bu.u[1]) : "v"(h0.z), "v"(h0.w));
        asm("v_cvt_pk_bf16_f32 %0, %1, %2" : "=v"(bu.u[2]) : "v"(h1.x), "v"(h1.y));
        asm("v_cvt_pk_bf16_f32 %0, %1, %2" : "=v"(bu.u[3]) : "v"(h1.z), "v"(h1.w));
        bf16x8 bfrag = bu.v;
        bf16x8 af0 = *(const bf16x8*)&Wbf[(l15 * 128 + kc * 32 + l4 * 8) ^ ((l15 & 7) << 3)];
        bf16x8 af1 = *(const bf16x8*)&Wbf[((16 + l15) * 128 + kc * 32 + l4 * 8) ^ (((16 + l15) & 7) << 3)];
        acc0 = __builtin_amdgcn_mfma_f32_16x16x32_bf16(af0, bfrag, acc0, 0, 0, 0);
        acc1 = __builtin_amdgcn_mfma_f32_16x16x32_bf16(af1, bfrag, acc1, 0, 0, 0);
    }

    // src/dst dots from accumulators
    float sv = 0.f, dvv = 0.f;
    #pragma unroll
    for (int r = 0; r < 4; ++r) {
        int f0 = l4 * 4 + r;
        sv  += acc0[r] * a[h * 64 + f0]      + acc1[r] * a[h * 64 + 16 + f0];
        dvv += acc0[r] * a[h * 64 + 32 + f0] + acc1[r] * a[h * 64 + 48 + f0];
    }
    sv  += __shfl_xor(sv, 16);  sv  += __shfl_xor(sv, 32);
    dvv += __shfl_xor(dvv, 16); dvv += __shfl_xor(dvv, 32);
    if (l4 == 0) { src[bh * 2048 + n] = sv; dst[bh * 2048 + n] = dvv; }

    // HtT via LDS transpose (reuse Wbf as T[32 f][64 n]) for coalesced 16B stores
    __syncthreads();
    ushort* T = Wbf;
    int nl = w * 16 + l15;
    #pragma unroll
    for (int r = 0; r < 4; ++r) {
        int f0 = l4 * 4 + r;
        T[f0 * 64 + nl]        = f2b(acc0[r]);
        T[(16 + f0) * 64 + nl] = f2b(acc1[r]);
    }
    __syncthreads();
    {
        int f = t >> 3, n8 = (t & 7) * 8;
        uint4 v = *(const uint4*)&T[f * 64 + n8];
        *(uint4*)((ushort*)HtT + (size_t)(bh * 32 + f) * 2048 + ntile * 64 + n8) = v;
    }
}

// ---------------- fused: softmax -> alpha (plain store) -> MFMA -> ELU -> H_new ------------
// grid (64 mtiles of 32 rows, 16 bh), block 256 (4 waves). 4 blocks/CU (VGPR cap 128).
// As double-buffered: ONE lgkm-only barrier per K-chunk; loads always issued before stores.
__global__ __launch_bounds__(256, 4) void k2_fused(const unsigned char* __restrict__ adjI,
                                                   const float* __restrict__ src,
                                                   const float* __restrict__ dst,
                                                   const __hip_bfloat16* __restrict__ HtT,
                                                   float* __restrict__ alpha,
                                                   float* __restrict__ outH) {
    __shared__ float dstS[2048];                      // 8 KB (pre-scaled by LOG2E)
    __shared__ float rowL[32], rowSrcS[32];
    __shared__ __align__(16) ushort As[2][32 * 128];  // 16 KB dbuf, XOR-swizzled

    int t = threadIdx.x;
    int mtile = blockIdx.x;   // 64
    int bh    = blockIdx.y;   // 16
    int lane = t & 63, w = t >> 6;
    int b = bh >> 2, h = bh & 3;
    int row0 = mtile * 32;

    const float4* dst4g = (const float4*)(dst + bh * 2048);
    #pragma unroll
    for (int u = 0; u < 2; ++u) {
        float4 v = dst4g[u * 256 + t];
        v.x *= LOG2E; v.y *= LOG2E; v.z *= LOG2E; v.w *= LOG2E;
        *(float4*)&dstS[(u * 256 + t) * 4] = v;
    }
    if (t < 32) rowSrcS[t] = src[bh * 2048 + row0 + t] * LOG2E;
    __syncthreads();

    // ---- pass A: per-row S = sum_j adjI * exp2(leaky(ee)); store L = -log2(S) ----
    for (int rr = 0; rr < 8; ++rr) {
        int r = w * 8 + rr;
        int gr = row0 + r;
        float sn = rowSrcS[r];
        const uint4* a16 = (const uint4*)(adjI + (size_t)gr * 2048);
        float S = 0.f;
        #pragma unroll
        for (int u = 0; u < 2; ++u) {
            uint4 ab = a16[u * 64 + lane];
            int jb = (u * 64 + lane) * 16;
            u32 words[4] = {ab.x, ab.y, ab.z, ab.w};
            #pragma unroll
            for (int wq = 0; wq < 4; ++wq) {
                float4 dv = *(const float4*)&dstS[jb + wq * 4];
                float dj[4] = {dv.x, dv.y, dv.z, dv.w};
                #pragma unroll
                for (int q = 0; q < 4; ++q) {
                    float ajf = (float)((words[wq] >> (8 * q)) & 0xffu);
                    float ee = sn + dj[q];
                    float vm = fmaxf(ee, LRELU * ee);
                    S = fmaf(EXP2(vm), ajf, S);
                }
            }
        }
        #pragma unroll
        for (int off = 32; off; off >>= 1) S += __shfl_xor(S, off);
        if (lane == 0) rowL[r] = -__log2f(S);
    }
    __syncthreads();

    // ---- pass B ----
    f32x4 acc = {0.f, 0.f, 0.f, 0.f};
    int wr = w >> 1, wc = w & 1;
    int l15 = lane & 15, l4 = lane >> 4;
    int arow = wr * 16 + l15;
    const ushort* Bfp = (const ushort*)HtT + (size_t)(bh * 32 + wc * 16 + l15) * 2048 + l4 * 8;
    float* alphaRow = alpha + (size_t)(bh * 2048 + row0) * 2048;

    int sr = t >> 5;            // rows sr, sr+8, sr+16, sr+24
    int sc4 = t & 31;

    float snR[4], LR[4];
    #pragma unroll
    for (int u = 0; u < 4; ++u) { snR[u] = rowSrcS[sr + u * 8]; LR[u] = rowL[sr + u * 8]; }

    auto loadA = [&](int k, u32* ar) {
        #pragma unroll
        for (int u = 0; u < 4; ++u)
            ar[u] = *(const u32*)(adjI + (size_t)(row0 + sr + u * 8) * 2048 + k * 128 + sc4 * 4);
    };
    auto loadB = [&](int k, bf16x8* br) {
        #pragma unroll
        for (int kk = 0; kk < 4; ++kk)
            br[kk] = *(const bf16x8*)(Bfp + (size_t)k * 128 + kk * 32);
    };
    auto stage = [&](int k, const u32* ar, ushort* Asb) {
        int jb = k * 128 + sc4 * 4;
        float4 dv = *(const float4*)&dstS[jb];
        float dj[4] = {dv.x, dv.y, dv.z, dv.w};
        #pragma unroll
        for (int u = 0; u < 4; ++u) {
            int r = sr + u * 8;
            float sn = snR[u], L = LR[u];
            u32 ab = ar[u];
            float o[4];
            #pragma unroll
            for (int q = 0; q < 4; ++q) {
                float ajf = (float)((ab >> (8 * q)) & 0xffu);
                float ee = sn + dj[q];
                float vm = fmaxf(ee + L, fmaf(ee, LRELU, L));
                o[q] = EXP2(vm) * ajf;
            }
            f32x4 ov = {o[0], o[1], o[2], o[3]};
            *(f32x4*)(alphaRow + (size_t)r * 2048 + jb) = ov;   // plain store (acks at L2)
            u32 lo, hi;
            asm("v_cvt_pk_bf16_f32 %0, %1, %2" : "=v"(lo) : "v"(o[0]), "v"(o[1]));
            asm("v_cvt_pk_bf16_f32 %0, %1, %2" : "=v"(hi) : "v"(o[2]), "v"(o[3]));
            uint2 pk = {lo, hi};
            *(uint2*)&Asb[(r * 128 + sc4 * 4) ^ ((r & 7) << 3)] = pk;
        }
    };
    auto mfmaPhase = [&](const bf16x8* br, const ushort* Asb) {
        #pragma unroll
        for (int kk = 0; kk < 4; ++kk) {
            bf16x8 af = *(const bf16x8*)&Asb[(arow * 128 + kk * 32 + l4 * 8) ^ ((arow & 7) << 3)];
            acc = __builtin_amdgcn_mfma_f32_16x16x32_bf16(af, br[kk], acc, 0, 0, 0);
        }
    };

    u32 aE[4], aO[4];
    bf16x8 bE[4], bO[4];
    loadA(0, aE); loadB(0, bE);   // prologue: chunk 0 -> set E

    for (int kp = 0; kp < 8; ++kp) {
        int ke = 2 * kp, ko = 2 * kp + 1;
        // -------- even chunk: prefetch ko (loads FIRST), stage ke, 1 barrier, MFMA --------
        loadA(ko, aO); loadB(ko, bO);
        __builtin_amdgcn_sched_barrier(0);
        stage(ke, aE, As[0]);
        asm volatile("s_waitcnt lgkmcnt(0)" ::: "memory");
        __builtin_amdgcn_s_barrier();
        mfmaPhase(bE, As[0]);
        // -------- odd chunk --------
        if (ko + 1 < 16) { loadA(ko + 1, aE); loadB(ko + 1, bE); }
        __builtin_amdgcn_sched_barrier(0);
        stage(ko, aO, As[1]);
        asm volatile("s_waitcnt lgkmcnt(0)" ::: "memory");
        __builtin_amdgcn_s_barrier();
        mfmaPhase(bO, As[1]);
    }

    // epilogue: ELU + write H_new[b][node][h*32 + col]
    #pragma unroll
    for (int q = 0; q < 4; ++q) {
        int node = row0 + wr * 16 + l4 * 4 + q;
        float v = acc[q];
        v = (v > 0.f) ? v : expm1f(v);
        outH[(size_t)(b * 2048 + node) * 128 + h * 32 + wc * 16 + l15] = v;
    }
}

extern "C" void kernel_launch(void* const* d_in, const int* in_sizes, int n_in,
                              void* d_out, int out_size, void* d_ws, size_t ws_size,
                              hipStream_t stream) {
    const float* H   = (const float*)d_in[0];
    const float* adj = (const float*)d_in[1];
    const float* W   = (const float*)d_in[2];
    const float* a   = (const float*)d_in[3];

    float* outH  = (float*)d_out;
    float* alpha = outH + (size_t)4 * 2048 * 128;   // 1048576

    char* ws = (char*)d_ws;
    __hip_bfloat16* HtT = (__hip_bfloat16*)ws;                    // 2 MB
    float* src = (float*)(ws + 2 * 1024 * 1024);                  // 128 KB
    float* dst = src + 32768;                                     // 128 KB
    unsigned char* adjI = (unsigned char*)(ws + 2 * 1024 * 1024 + 256 * 1024);  // 4 MB

    k01<<<4608, 256, 0, stream>>>(adj, adjI, H, W, a, HtT, src, dst);
    k2_fused<<<dim3(64, 16), 256, 0, stream>>>(adjI, src, dst, HtT, alpha, outH);
}